// Round 4
// baseline (218.541 us; speedup 1.0000x reference)
//
#include <hip/hip_runtime.h>

#define PLACEHOLDER (-1)
#define KB 8     // blocks (slices) per request
#define T  256   // threads per block

__device__ __forceinline__ void comb(float& v, int& i, float v2, int i2) {
    // argmax combine, numpy tie-break: lower index wins on equal value
    if (v2 > v || (v2 == v && i2 < i)) { v = v2; i = i2; }
}

// block-wide argmax; result broadcast to all threads
__device__ __forceinline__ void block_argmax(float& bv, int& bi, float* s_v, int* s_i) {
    #pragma unroll
    for (int off = 32; off > 0; off >>= 1) {
        float v2 = __shfl_down(bv, off);
        int   i2 = __shfl_down(bi, off);
        comb(bv, bi, v2, i2);
    }
    const int tid = threadIdx.x;
    if ((tid & 63) == 0) { s_v[tid >> 6] = bv; s_i[tid >> 6] = bi; }
    __syncthreads();
    if (tid == 0) {
        for (int w = 1; w < (T >> 6); ++w) comb(bv, bi, s_v[w], s_i[w]);
        s_v[0] = bv; s_i[0] = bi;
    }
    __syncthreads();
    bv = s_v[0]; bi = s_i[0];
    __syncthreads();
}

// is_greedy may arrive as 1-byte bools, int32, or float32 — detect from content
__device__ __forceinline__ bool detect_greedy(const void* grd, int b, int B, int* s_flags) {
    const int tid = threadIdx.x;
    if (tid < 2) s_flags[tid] = 0;
    __syncthreads();
    const unsigned char* gb = (const unsigned char*)grd;
    for (int t = tid; t < B; t += T) {
        unsigned char c = gb[t];
        if (c > 1) s_flags[0] = 1;          // bytes beyond {0,1} -> f32 payload
        if ((t & 3) && c) s_flags[1] = 1;   // nonzero off-word byte -> byte bools
    }
    __syncthreads();
    bool g;
    if (s_flags[0])      g = (((const float*)grd)[b] != 0.0f);
    else if (s_flags[1]) g = (gb[b] != 0);
    else                 g = (((const int*)grd)[b] != 0);
    return g;
}

__device__ __forceinline__ unsigned long long pack_vi(float v, int i) {
    // all candidate values >= 0 -> float bit pattern is order-preserving as uint
    return ((unsigned long long)__float_as_uint(v) << 32)
         | (unsigned long long)(0xFFFFFFFFu - (unsigned)i);
}
__device__ __forceinline__ int unpack_i(unsigned long long pk) {
    return (int)(0xFFFFFFFFu - (unsigned)(pk & 0xFFFFFFFFull));
}

__global__ __launch_bounds__(T) void fused_all(
    const float* __restrict__ dp, const float* __restrict__ tp,
    const float* __restrict__ up, const float* __restrict__ q,
    const int* __restrict__ cu, const int* __restrict__ did,
    const int* __restrict__ bonus, const void* __restrict__ grd,
    int* __restrict__ out, unsigned long long* __restrict__ packed,
    int* __restrict__ count, int B, int V, int S)
{
    const int b = blockIdx.x / KB, slice = blockIdx.x % KB;
    const int tid = threadIdx.x;
    __shared__ int   s_flags[2];
    __shared__ float s_v[T >> 6];
    __shared__ int   s_i[T >> 6];
    __shared__ int   sh_fr, sh_last;

    const bool g   = detect_greedy(grd, b, B, s_flags);
    const int start = b ? cu[b - 1] : 0;
    const int len   = cu[b] - start;
    const int V4    = V >> 2;

    // ---- prepass (redundant per slice): find the one heavy-scan row ----
    int scan_row = -1, kind = 0;
    int fr = len;
    if (g) {
        scan_row = start; kind = 1;
    } else {
        if (tid < 64) {
            bool acc = true;
            if (tid < len) {
                const int i  = start + tid;
                const int td = did[i];
                const float dat = dp[(size_t)i * V + td];
                const float tat = tp[(size_t)i * V + td];
                acc = (dat > 0.0f && tat >= up[i] * dat);
            }
            const unsigned long long rej =
                (~__ballot(acc)) & ((len >= 64) ? ~0ull : ((1ull << len) - 1ull));
            if (tid == 0) sh_fr = rej ? (__ffsll((long long)rej) - 1) : len;
        }
        __syncthreads();
        fr = sh_fr;
        if (fr < len) scan_row = start + fr;   // first rejected row needs recovery scan
    }

    // ---- heavy scan of this block's 1/KB slice ----
    if (scan_row >= 0) {
        const int c4 = (V4 + KB - 1) / KB;
        const int j0 = slice * c4;
        const int j1 = min(j0 + c4, V4);
        float bv = 0.0f; int bi = 0x7FFFFFFF;   // loses all ties; safe if lane idle
        if (kind) {
            const float4* t4 = (const float4*)(tp + (size_t)scan_row * V);
            for (int j = j0 + tid; j < j1; j += T) {
                const float4 t = t4[j]; const int base = j << 2;
                if (t.x > bv) { bv = t.x; bi = base;     }
                if (t.y > bv) { bv = t.y; bi = base + 1; }
                if (t.z > bv) { bv = t.z; bi = base + 2; }
                if (t.w > bv) { bv = t.w; bi = base + 3; }
            }
            if (slice == KB - 1)
                for (int j = (V4 << 2) + tid; j < V; j += T) {
                    const float tv = tp[(size_t)scan_row * V + j];
                    if (tv > bv) { bv = tv; bi = j; }
                }
        } else {
            const float4* t4 = (const float4*)(tp + (size_t)scan_row * V);
            const float4* d4 = (const float4*)(dp + (size_t)scan_row * V);
            const float4* q4 = (const float4*)(q  + (size_t)b * V);
            for (int j = j0 + tid; j < j1; j += T) {
                const float4 t = t4[j], d = d4[j], qq = q4[j];
                const int base = j << 2;
                float r;
                r = fmaxf(t.x - d.x, 0.0f) / qq.x; if (r > bv) { bv = r; bi = base;     }
                r = fmaxf(t.y - d.y, 0.0f) / qq.y; if (r > bv) { bv = r; bi = base + 1; }
                r = fmaxf(t.z - d.z, 0.0f) / qq.z; if (r > bv) { bv = r; bi = base + 2; }
                r = fmaxf(t.w - d.w, 0.0f) / qq.w; if (r > bv) { bv = r; bi = base + 3; }
            }
            if (slice == KB - 1)
                for (int j = (V4 << 2) + tid; j < V; j += T) {
                    const float r = fmaxf(tp[(size_t)scan_row * V + j]
                                          - dp[(size_t)scan_row * V + j], 0.0f)
                                    / q[(size_t)b * V + j];
                    if (r > bv) { bv = r; bi = j; }
                }
        }
        block_argmax(bv, bi, s_v, s_i);
        if (tid == 0) atomicMax(&packed[b], pack_vi(bv, bi));
    }

    // ---- last block of this request finalizes all its outputs ----
    __threadfence();
    if (tid == 0) sh_last = (atomicAdd(&count[b], 1) == KB - 1) ? 1 : 0;
    __syncthreads();
    if (!sh_last) return;

    const unsigned long long pk = atomicMax(&packed[b], 0ull);  // device-scope read
    int* row = out + b * (S + 1);

    if (!g) {
        if (tid == 0) {
            for (int p = 0; p < fr; ++p) row[p] = did[start + p];
            if (fr < len) {
                row[fr] = unpack_i(pk);
                for (int r = fr + 1; r <= S; ++r) row[r] = PLACEHOLDER;
            } else {
                row[len] = bonus[b];
                for (int r = len + 1; r <= S; ++r) row[r] = PLACEHOLDER;
            }
        }
        return;
    }

    // greedy: scanned argmax is row 0's token
    const int tok0 = unpack_i(pk);
    if (tid == 0) row[0] = tok0;
    bool ok = (did[start] == tok0);
    int p = 1;
    for (; p < len && ok; ++p) {   // statistically never entered (match prob ~1/V)
        const float4* t4 = (const float4*)(tp + (size_t)(start + p) * V);
        float bv = 0.0f; int bi = 0x7FFFFFFF;
        for (int j = tid; j < V4; j += T) {
            const float4 t = t4[j]; const int base = j << 2;
            if (t.x > bv) { bv = t.x; bi = base;     }
            if (t.y > bv) { bv = t.y; bi = base + 1; }
            if (t.z > bv) { bv = t.z; bi = base + 2; }
            if (t.w > bv) { bv = t.w; bi = base + 3; }
        }
        for (int j = (V4 << 2) + tid; j < V; j += T) {
            const float tv = tp[(size_t)(start + p) * V + j];
            if (tv > bv) { bv = tv; bi = j; }
        }
        block_argmax(bv, bi, s_v, s_i);
        if (tid == 0) row[p] = bi;
        ok = (did[start + p] == bi);
    }
    if (tid == 0) {
        for (int r = p; r <= S; ++r) row[r] = PLACEHOLDER;
        if (ok) row[len] = bonus[b];
    }
}

extern "C" void kernel_launch(void* const* d_in, const int* in_sizes, int n_in,
                              void* d_out, int out_size, void* d_ws, size_t ws_size,
                              hipStream_t stream) {
    const float* dp  = (const float*)d_in[0];   // draft_probs  [N,V]
    const float* tp  = (const float*)d_in[1];   // target_probs [N,V]
    const float* up  = (const float*)d_in[2];   // uniform_probs [N]
    const float* q   = (const float*)d_in[3];   // q [B,V]
    const int*   cu  = (const int*)d_in[4];     // cu_num_draft_tokens [B]
    const int*   did = (const int*)d_in[5];     // draft_token_ids [N]
    const int*   bon = (const int*)d_in[6];     // bonus_token_ids [B]
    const void*  grd = d_in[7];                 // is_greedy [B]

    const int B = in_sizes[4];
    const int N = in_sizes[5];
    const int V = in_sizes[0] / N;
    const int S = out_size / B - 1;

    unsigned long long* packed = (unsigned long long*)d_ws;       // [B]
    int* count = (int*)((char*)d_ws + (size_t)B * 8);             // [B]

    // packed=0 decodes to (value 0.0, index 2^32-1): loses to any real candidate.
    hipMemsetAsync(d_ws, 0, (size_t)B * 12, stream);

    fused_all<<<B * KB, T, 0, stream>>>(dp, tp, up, q, cu, did, bon, grd,
                                        (int*)d_out, packed, count, B, V, S);
}

// Round 5
// 217.760 us; speedup vs baseline: 1.0036x; 1.0036x over previous
//
#include <hip/hip_runtime.h>

#define PLACEHOLDER (-1)
#define KB 8     // blocks (slices) per request
#define T  256   // threads per block
#define CELL_STRIDE 128   // one cache line per request: {packed u64, count int}

__device__ __forceinline__ void comb(float& v, int& i, float v2, int i2) {
    // argmax combine, numpy tie-break: lower index wins on equal value
    if (v2 > v || (v2 == v && i2 < i)) { v = v2; i = i2; }
}

// block-wide argmax; result broadcast to all threads
__device__ __forceinline__ void block_argmax(float& bv, int& bi, float* s_v, int* s_i) {
    #pragma unroll
    for (int off = 32; off > 0; off >>= 1) {
        float v2 = __shfl_down(bv, off);
        int   i2 = __shfl_down(bi, off);
        comb(bv, bi, v2, i2);
    }
    const int tid = threadIdx.x;
    if ((tid & 63) == 0) { s_v[tid >> 6] = bv; s_i[tid >> 6] = bi; }
    __syncthreads();
    if (tid == 0) {
        for (int w = 1; w < (T >> 6); ++w) comb(bv, bi, s_v[w], s_i[w]);
        s_v[0] = bv; s_i[0] = bi;
    }
    __syncthreads();
    bv = s_v[0]; bi = s_i[0];
    __syncthreads();
}

// is_greedy may arrive as 1-byte bools, int32, or float32 — detect from content
__device__ __forceinline__ bool detect_greedy(const void* grd, int b, int B, int* s_flags) {
    const int tid = threadIdx.x;
    if (tid < 2) s_flags[tid] = 0;
    __syncthreads();
    const unsigned char* gb = (const unsigned char*)grd;
    for (int t = tid; t < B; t += T) {
        unsigned char c = gb[t];
        if (c > 1) s_flags[0] = 1;          // bytes beyond {0,1} -> f32 payload
        if ((t & 3) && c) s_flags[1] = 1;   // nonzero off-word byte -> byte bools
    }
    __syncthreads();
    bool g;
    if (s_flags[0])      g = (((const float*)grd)[b] != 0.0f);
    else if (s_flags[1]) g = (gb[b] != 0);
    else                 g = (((const int*)grd)[b] != 0);
    return g;
}

__device__ __forceinline__ unsigned long long pack_vi(float v, int i) {
    // all candidate values >= 0 -> float bit pattern is order-preserving as uint
    return ((unsigned long long)__float_as_uint(v) << 32)
         | (unsigned long long)(0xFFFFFFFFu - (unsigned)i);
}
__device__ __forceinline__ int unpack_i(unsigned long long pk) {
    return (int)(0xFFFFFFFFu - (unsigned)(pk & 0xFFFFFFFFull));
}

__global__ __launch_bounds__(T) void fused_all(
    const float* __restrict__ dp, const float* __restrict__ tp,
    const float* __restrict__ up, const float* __restrict__ q,
    const int* __restrict__ cu, const int* __restrict__ did,
    const int* __restrict__ bonus, const void* __restrict__ grd,
    int* __restrict__ out, char* __restrict__ cells, int B, int V, int S)
{
    const int b = blockIdx.x / KB, slice = blockIdx.x % KB;
    const int tid = threadIdx.x;
    unsigned long long* packed = (unsigned long long*)(cells + (size_t)b * CELL_STRIDE);
    int* count = (int*)(cells + (size_t)b * CELL_STRIDE + 8);

    __shared__ int   s_flags[2];
    __shared__ float s_v[T >> 6];
    __shared__ int   s_i[T >> 6];
    __shared__ int   sh_fr, sh_last;
    __shared__ unsigned long long sh_pk;

    const bool g   = detect_greedy(grd, b, B, s_flags);
    const int start = b ? cu[b - 1] : 0;
    const int len   = cu[b] - start;
    const int V4    = V >> 2;

    // ---- prepass (redundant per slice): find the one heavy-scan row ----
    int scan_row = -1, kind = 0;
    int fr = len;
    if (g) {
        scan_row = start; kind = 1;
    } else {
        if (tid < 64) {
            bool acc = true;
            if (tid < len) {
                const int i  = start + tid;
                const int td = did[i];
                const float dat = dp[(size_t)i * V + td];
                const float tat = tp[(size_t)i * V + td];
                acc = (dat > 0.0f && tat >= up[i] * dat);
            }
            const unsigned long long rej =
                (~__ballot(acc)) & ((len >= 64) ? ~0ull : ((1ull << len) - 1ull));
            if (tid == 0) sh_fr = rej ? (__ffsll((long long)rej) - 1) : len;
        }
        __syncthreads();
        fr = sh_fr;
        if (fr < len) scan_row = start + fr;   // first rejected row needs recovery scan
    }

    // ---- heavy scan of this block's 1/KB slice ----
    if (scan_row >= 0) {
        const int c4 = (V4 + KB - 1) / KB;
        const int j0 = slice * c4;
        const int j1 = min(j0 + c4, V4);
        float bv = 0.0f; int bi = 0x7FFFFFFF;   // loses all ties; safe if lane idle
        if (kind) {
            const float4* t4 = (const float4*)(tp + (size_t)scan_row * V);
            for (int j = j0 + tid; j < j1; j += T) {
                const float4 t = t4[j]; const int base = j << 2;
                if (t.x > bv) { bv = t.x; bi = base;     }
                if (t.y > bv) { bv = t.y; bi = base + 1; }
                if (t.z > bv) { bv = t.z; bi = base + 2; }
                if (t.w > bv) { bv = t.w; bi = base + 3; }
            }
            if (slice == KB - 1)
                for (int j = (V4 << 2) + tid; j < V; j += T) {
                    const float tv = tp[(size_t)scan_row * V + j];
                    if (tv > bv) { bv = tv; bi = j; }
                }
        } else {
            const float4* t4 = (const float4*)(tp + (size_t)scan_row * V);
            const float4* d4 = (const float4*)(dp + (size_t)scan_row * V);
            const float4* q4 = (const float4*)(q  + (size_t)b * V);
            for (int j = j0 + tid; j < j1; j += T) {
                const float4 t = t4[j], d = d4[j], qq = q4[j];
                const int base = j << 2;
                float r;
                r = fmaxf(t.x - d.x, 0.0f) / qq.x; if (r > bv) { bv = r; bi = base;     }
                r = fmaxf(t.y - d.y, 0.0f) / qq.y; if (r > bv) { bv = r; bi = base + 1; }
                r = fmaxf(t.z - d.z, 0.0f) / qq.z; if (r > bv) { bv = r; bi = base + 2; }
                r = fmaxf(t.w - d.w, 0.0f) / qq.w; if (r > bv) { bv = r; bi = base + 3; }
            }
            if (slice == KB - 1)
                for (int j = (V4 << 2) + tid; j < V; j += T) {
                    const float r = fmaxf(tp[(size_t)scan_row * V + j]
                                          - dp[(size_t)scan_row * V + j], 0.0f)
                                    / q[(size_t)b * V + j];
                    if (r > bv) { bv = r; bi = j; }
                }
        }
        block_argmax(bv, bi, s_v, s_i);
        if (tid == 0) atomicMax(packed, pack_vi(bv, bi));
    }

    // ---- last block of this request finalizes all its outputs ----
    __threadfence();
    if (tid == 0) {
        sh_last = (atomicAdd(count, 1) == KB - 1) ? 1 : 0;
        // single-thread device-scope RMW read (round 4's 65K-thread version
        // serialized ~300us on same-line atomic contention)
        sh_pk = sh_last ? atomicMax(packed, 0ull) : 0ull;
    }
    __syncthreads();
    if (!sh_last) return;
    const unsigned long long pk = sh_pk;
    int* row = out + b * (S + 1);

    if (!g) {
        if (tid == 0) {
            for (int p = 0; p < fr; ++p) row[p] = did[start + p];
            if (fr < len) {
                row[fr] = unpack_i(pk);
                for (int r = fr + 1; r <= S; ++r) row[r] = PLACEHOLDER;
            } else {
                row[len] = bonus[b];
                for (int r = len + 1; r <= S; ++r) row[r] = PLACEHOLDER;
            }
        }
        return;
    }

    // greedy: scanned argmax is row 0's token
    const int tok0 = unpack_i(pk);
    if (tid == 0) row[0] = tok0;
    bool ok = (did[start] == tok0);
    int p = 1;
    for (; p < len && ok; ++p) {   // statistically never entered (match prob ~1/V)
        const float4* t4 = (const float4*)(tp + (size_t)(start + p) * V);
        float bv = 0.0f; int bi = 0x7FFFFFFF;
        for (int j = tid; j < V4; j += T) {
            const float4 t = t4[j]; const int base = j << 2;
            if (t.x > bv) { bv = t.x; bi = base;     }
            if (t.y > bv) { bv = t.y; bi = base + 1; }
            if (t.z > bv) { bv = t.z; bi = base + 2; }
            if (t.w > bv) { bv = t.w; bi = base + 3; }
        }
        for (int j = (V4 << 2) + tid; j < V; j += T) {
            const float tv = tp[(size_t)(start + p) * V + j];
            if (tv > bv) { bv = tv; bi = j; }
        }
        block_argmax(bv, bi, s_v, s_i);
        if (tid == 0) row[p] = bi;
        ok = (did[start + p] == bi);
    }
    if (tid == 0) {
        for (int r = p; r <= S; ++r) row[r] = PLACEHOLDER;
        if (ok) row[len] = bonus[b];
    }
}

extern "C" void kernel_launch(void* const* d_in, const int* in_sizes, int n_in,
                              void* d_out, int out_size, void* d_ws, size_t ws_size,
                              hipStream_t stream) {
    const float* dp  = (const float*)d_in[0];   // draft_probs  [N,V]
    const float* tp  = (const float*)d_in[1];   // target_probs [N,V]
    const float* up  = (const float*)d_in[2];   // uniform_probs [N]
    const float* q   = (const float*)d_in[3];   // q [B,V]
    const int*   cu  = (const int*)d_in[4];     // cu_num_draft_tokens [B]
    const int*   did = (const int*)d_in[5];     // draft_token_ids [N]
    const int*   bon = (const int*)d_in[6];     // bonus_token_ids [B]
    const void*  grd = d_in[7];                 // is_greedy [B]

    const int B = in_sizes[4];
    const int N = in_sizes[5];
    const int V = in_sizes[0] / N;
    const int S = out_size / B - 1;

    char* cells = (char*)d_ws;   // per-request 128B cell: {packed u64, count}
    // packed=0 decodes to (value 0.0, index 2^32-1): loses to any real candidate.
    hipMemsetAsync(cells, 0, (size_t)B * CELL_STRIDE, stream);

    fused_all<<<B * KB, T, 0, stream>>>(dp, tp, up, q, cu, did, bon, grd,
                                        (int*)d_out, cells, B, V, S);
}

// Round 6
// 23.860 us; speedup vs baseline: 9.1591x; 9.1264x over previous
//
#include <hip/hip_runtime.h>

#define PLACEHOLDER (-1)
#define KB 8     // blocks (slices) per request
#define T  256   // threads per block
#define CELL_STRIDE 128   // one cache line per request: {packed u64, count int}

__device__ __forceinline__ void comb(float& v, int& i, float v2, int i2) {
    // argmax combine, numpy tie-break: lower index wins on equal value
    if (v2 > v || (v2 == v && i2 < i)) { v = v2; i = i2; }
}

// block-wide argmax; result broadcast to all threads
__device__ __forceinline__ void block_argmax(float& bv, int& bi, float* s_v, int* s_i) {
    #pragma unroll
    for (int off = 32; off > 0; off >>= 1) {
        float v2 = __shfl_down(bv, off);
        int   i2 = __shfl_down(bi, off);
        comb(bv, bi, v2, i2);
    }
    const int tid = threadIdx.x;
    if ((tid & 63) == 0) { s_v[tid >> 6] = bv; s_i[tid >> 6] = bi; }
    __syncthreads();
    if (tid == 0) {
        for (int w = 1; w < (T >> 6); ++w) comb(bv, bi, s_v[w], s_i[w]);
        s_v[0] = bv; s_i[0] = bi;
    }
    __syncthreads();
    bv = s_v[0]; bi = s_i[0];
    __syncthreads();
}

// is_greedy may arrive as 1-byte bools, int32, or float32 — detect from content
__device__ __forceinline__ bool detect_greedy(const void* grd, int b, int B, int* s_flags) {
    const int tid = threadIdx.x;
    if (tid < 2) s_flags[tid] = 0;
    __syncthreads();
    const unsigned char* gb = (const unsigned char*)grd;
    for (int t = tid; t < B; t += T) {
        unsigned char c = gb[t];
        if (c > 1) s_flags[0] = 1;          // bytes beyond {0,1} -> f32 payload
        if ((t & 3) && c) s_flags[1] = 1;   // nonzero off-word byte -> byte bools
    }
    __syncthreads();
    bool g;
    if (s_flags[0])      g = (((const float*)grd)[b] != 0.0f);
    else if (s_flags[1]) g = (gb[b] != 0);
    else                 g = (((const int*)grd)[b] != 0);
    return g;
}

__device__ __forceinline__ unsigned long long pack_vi(float v, int i) {
    // all candidate values >= 0 -> float bit pattern is order-preserving as uint
    return ((unsigned long long)__float_as_uint(v) << 32)
         | (unsigned long long)(0xFFFFFFFFu - (unsigned)i);
}
__device__ __forceinline__ int unpack_i(unsigned long long pk) {
    return (int)(0xFFFFFFFFu - (unsigned)(pk & 0xFFFFFFFFull));
}

__global__ __launch_bounds__(T) void fused_all(
    const float* __restrict__ dp, const float* __restrict__ tp,
    const float* __restrict__ up, const float* __restrict__ q,
    const int* __restrict__ cu, const int* __restrict__ did,
    const int* __restrict__ bonus, const void* __restrict__ grd,
    int* __restrict__ out, char* __restrict__ cells, int B, int V, int S)
{
    const int b = blockIdx.x / KB, slice = blockIdx.x % KB;
    const int tid = threadIdx.x;
    unsigned long long* packed = (unsigned long long*)(cells + (size_t)b * CELL_STRIDE);
    int* count = (int*)(cells + (size_t)b * CELL_STRIDE + 8);

    __shared__ int   s_flags[2];
    __shared__ float s_v[T >> 6];
    __shared__ int   s_i[T >> 6];
    __shared__ int   sh_fr, sh_last;
    __shared__ unsigned long long sh_pk;

    const bool g   = detect_greedy(grd, b, B, s_flags);
    const int start = b ? cu[b - 1] : 0;
    const int len   = cu[b] - start;
    const int V4    = V >> 2;

    // ---- prepass (redundant per slice): find the one heavy-scan row ----
    int scan_row = -1, kind = 0;
    int fr = len;
    if (g) {
        scan_row = start; kind = 1;
    } else {
        if (tid < 64) {
            bool acc = true;
            if (tid < len) {
                const int i  = start + tid;
                const int td = did[i];
                const float dat = dp[(size_t)i * V + td];
                const float tat = tp[(size_t)i * V + td];
                acc = (dat > 0.0f && tat >= up[i] * dat);
            }
            const unsigned long long rej =
                (~__ballot(acc)) & ((len >= 64) ? ~0ull : ((1ull << len) - 1ull));
            if (tid == 0) sh_fr = rej ? (__ffsll((long long)rej) - 1) : len;
        }
        __syncthreads();
        fr = sh_fr;
        if (fr < len) scan_row = start + fr;   // first rejected row needs recovery scan
    }

    // ---- heavy scan of this block's 1/KB slice ----
    int ordered_one = 1;   // stays 1; forces vmcnt-wait on our atomicMax ack
    if (scan_row >= 0) {
        const int c4 = (V4 + KB - 1) / KB;
        const int j0 = slice * c4;
        const int j1 = min(j0 + c4, V4);
        float bv = 0.0f; int bi = 0x7FFFFFFF;   // loses all ties; safe if lane idle
        if (kind) {
            const float4* t4 = (const float4*)(tp + (size_t)scan_row * V);
            for (int j = j0 + tid; j < j1; j += T) {
                const float4 t = t4[j]; const int base = j << 2;
                if (t.x > bv) { bv = t.x; bi = base;     }
                if (t.y > bv) { bv = t.y; bi = base + 1; }
                if (t.z > bv) { bv = t.z; bi = base + 2; }
                if (t.w > bv) { bv = t.w; bi = base + 3; }
            }
            if (slice == KB - 1)
                for (int j = (V4 << 2) + tid; j < V; j += T) {
                    const float tv = tp[(size_t)scan_row * V + j];
                    if (tv > bv) { bv = tv; bi = j; }
                }
        } else {
            const float4* t4 = (const float4*)(tp + (size_t)scan_row * V);
            const float4* d4 = (const float4*)(dp + (size_t)scan_row * V);
            const float4* q4 = (const float4*)(q  + (size_t)b * V);
            for (int j = j0 + tid; j < j1; j += T) {
                const float4 t = t4[j], d = d4[j], qq = q4[j];
                const int base = j << 2;
                float r;
                r = fmaxf(t.x - d.x, 0.0f) / qq.x; if (r > bv) { bv = r; bi = base;     }
                r = fmaxf(t.y - d.y, 0.0f) / qq.y; if (r > bv) { bv = r; bi = base + 1; }
                r = fmaxf(t.z - d.z, 0.0f) / qq.z; if (r > bv) { bv = r; bi = base + 2; }
                r = fmaxf(t.w - d.w, 0.0f) / qq.w; if (r > bv) { bv = r; bi = base + 3; }
            }
            if (slice == KB - 1)
                for (int j = (V4 << 2) + tid; j < V; j += T) {
                    const float r = fmaxf(tp[(size_t)scan_row * V + j]
                                          - dp[(size_t)scan_row * V + j], 0.0f)
                                    / q[(size_t)b * V + j];
                    if (r > bv) { bv = r; bi = j; }
                }
        }
        block_argmax(bv, bi, s_v, s_i);
        if (tid == 0) {
            // returning atomicMax; its result feeds the count-add operand so the
            // add cannot issue before the max's ack (vmcnt data dependency).
            // Top bit of packed is always 0 (values are non-negative floats).
            unsigned long long old = atomicMax(packed, pack_vi(bv, bi));
            ordered_one = 1 + (int)(old >> 63);
        }
    }

    // ---- last block of this request finalizes all its outputs ----
    // NO __threadfence: round-4/5 showed 8192 wave-level device fences cost
    // ~290us (L2 writeback storms; per-XCD L2s are non-coherent). Device-scope
    // atomics are already performed at a device-coherent point; ordering comes
    // from the data dependency above.
    if (tid == 0) {
        sh_last = (atomicAdd(count, ordered_one) >= KB - 1) ? 1 : 0;
        sh_pk = sh_last ? atomicMax(packed, 0ull) : 0ull;   // coherent RMW read
    }
    __syncthreads();
    if (!sh_last) return;
    const unsigned long long pk = sh_pk;
    int* row = out + b * (S + 1);

    if (!g) {
        if (tid == 0) {
            for (int p = 0; p < fr; ++p) row[p] = did[start + p];
            if (fr < len) {
                row[fr] = unpack_i(pk);
                for (int r = fr + 1; r <= S; ++r) row[r] = PLACEHOLDER;
            } else {
                row[len] = bonus[b];
                for (int r = len + 1; r <= S; ++r) row[r] = PLACEHOLDER;
            }
        }
        return;
    }

    // greedy: scanned argmax is row 0's token
    const int tok0 = unpack_i(pk);
    if (tid == 0) row[0] = tok0;
    bool ok = (did[start] == tok0);
    int p = 1;
    for (; p < len && ok; ++p) {   // statistically never entered (match prob ~1/V)
        const float4* t4 = (const float4*)(tp + (size_t)(start + p) * V);
        float bv = 0.0f; int bi = 0x7FFFFFFF;
        for (int j = tid; j < V4; j += T) {
            const float4 t = t4[j]; const int base = j << 2;
            if (t.x > bv) { bv = t.x; bi = base;     }
            if (t.y > bv) { bv = t.y; bi = base + 1; }
            if (t.z > bv) { bv = t.z; bi = base + 2; }
            if (t.w > bv) { bv = t.w; bi = base + 3; }
        }
        for (int j = (V4 << 2) + tid; j < V; j += T) {
            const float tv = tp[(size_t)(start + p) * V + j];
            if (tv > bv) { bv = tv; bi = j; }
        }
        block_argmax(bv, bi, s_v, s_i);
        if (tid == 0) row[p] = bi;
        ok = (did[start + p] == bi);
    }
    if (tid == 0) {
        for (int r = p; r <= S; ++r) row[r] = PLACEHOLDER;
        if (ok) row[len] = bonus[b];
    }
}

extern "C" void kernel_launch(void* const* d_in, const int* in_sizes, int n_in,
                              void* d_out, int out_size, void* d_ws, size_t ws_size,
                              hipStream_t stream) {
    const float* dp  = (const float*)d_in[0];   // draft_probs  [N,V]
    const float* tp  = (const float*)d_in[1];   // target_probs [N,V]
    const float* up  = (const float*)d_in[2];   // uniform_probs [N]
    const float* q   = (const float*)d_in[3];   // q [B,V]
    const int*   cu  = (const int*)d_in[4];     // cu_num_draft_tokens [B]
    const int*   did = (const int*)d_in[5];     // draft_token_ids [N]
    const int*   bon = (const int*)d_in[6];     // bonus_token_ids [B]
    const void*  grd = d_in[7];                 // is_greedy [B]

    const int B = in_sizes[4];
    const int N = in_sizes[5];
    const int V = in_sizes[0] / N;
    const int S = out_size / B - 1;

    char* cells = (char*)d_ws;   // per-request 128B cell: {packed u64, count}
    // packed=0 decodes to (value 0.0, index 2^32-1): loses to any real candidate.
    hipMemsetAsync(cells, 0, (size_t)B * CELL_STRIDE, stream);

    fused_all<<<B * KB, T, 0, stream>>>(dp, tp, up, q, cu, did, bon, grd,
                                        (int*)d_out, cells, B, V, S);
}

// Round 7
// 17.571 us; speedup vs baseline: 12.4373x; 1.3579x over previous
//
#include <hip/hip_runtime.h>

#define PLACEHOLDER (-1)
#define T  1024   // threads per block (one block per request)
#define NW (T / 64)

__device__ __forceinline__ void comb(float& v, int& i, float v2, int i2) {
    // argmax combine, numpy tie-break: lower index wins on equal value
    if (v2 > v || (v2 == v && i2 < i)) { v = v2; i = i2; }
}

// block-wide argmax; result broadcast to all threads
__device__ __forceinline__ void block_argmax(float& bv, int& bi, float* s_v, int* s_i) {
    #pragma unroll
    for (int off = 32; off > 0; off >>= 1) {
        float v2 = __shfl_down(bv, off);
        int   i2 = __shfl_down(bi, off);
        comb(bv, bi, v2, i2);
    }
    const int tid = threadIdx.x;
    if ((tid & 63) == 0) { s_v[tid >> 6] = bv; s_i[tid >> 6] = bi; }
    __syncthreads();
    if (tid == 0) {
        for (int w = 1; w < NW; ++w) comb(bv, bi, s_v[w], s_i[w]);
        s_v[0] = bv; s_i[0] = bi;
    }
    __syncthreads();
    bv = s_v[0]; bi = s_i[0];
    __syncthreads();
}

// is_greedy may arrive as 1-byte bools, int32, or float32 — detect from content
__device__ __forceinline__ bool detect_greedy(const void* grd, int b, int B, int* s_flags) {
    const int tid = threadIdx.x;
    if (tid < 2) s_flags[tid] = 0;
    __syncthreads();
    const unsigned char* gb = (const unsigned char*)grd;
    for (int t = tid; t < B; t += T) {
        unsigned char c = gb[t];
        if (c > 1) s_flags[0] = 1;          // bytes beyond {0,1} -> f32 payload
        if ((t & 3) && c) s_flags[1] = 1;   // nonzero off-word byte -> byte bools
    }
    __syncthreads();
    bool g;
    if (s_flags[0])      g = (((const float*)grd)[b] != 0.0f);
    else if (s_flags[1]) g = (gb[b] != 0);
    else                 g = (((const int*)grd)[b] != 0);
    return g;
}

__global__ __launch_bounds__(T) void fused_one(
    const float* __restrict__ dp, const float* __restrict__ tp,
    const float* __restrict__ up, const float* __restrict__ q,
    const int* __restrict__ cu, const int* __restrict__ did,
    const int* __restrict__ bonus, const void* __restrict__ grd,
    int* __restrict__ out, int B, int V, int S)
{
    const int b = blockIdx.x, tid = threadIdx.x;
    __shared__ int   s_flags[2];
    __shared__ float s_v[NW];
    __shared__ int   s_i[NW];
    __shared__ int   sh_fr;

    const bool g    = detect_greedy(grd, b, B, s_flags);
    const int start = b ? cu[b - 1] : 0;
    const int len   = cu[b] - start;
    const int V4    = V >> 2;
    int* row = out + b * (S + 1);

    // ---- prepass: all accept-gathers in parallel (wave 0), ballot -> first reject ----
    int fr = len, scan_row = -1, kind = 0;
    if (g) {
        scan_row = start; kind = 1;       // greedy: row 0 target argmax needed
    } else {
        if (tid < 64) {
            bool acc = true;
            if (tid < len) {
                const int i  = start + tid;
                const int td = did[i];
                const float dat = dp[(size_t)i * V + td];
                const float tat = tp[(size_t)i * V + td];
                acc = (dat > 0.0f && tat >= up[i] * dat);
            }
            const unsigned long long rej =
                (~__ballot(acc)) & ((len >= 64) ? ~0ull : ((1ull << len) - 1ull));
            if (tid == 0) sh_fr = rej ? (__ffsll((long long)rej) - 1) : len;
        }
        __syncthreads();
        fr = sh_fr;
        if (fr < len) scan_row = start + fr;   // first rejected row: recovery scan
    }

    // ---- one heavy scan (if needed), full 1024-thread block ----
    float bv = 0.0f; int bi = 0x7FFFFFFF;   // loses all ties; safe for idle lanes
    if (scan_row >= 0) {
        if (kind) {
            const float4* t4 = (const float4*)(tp + (size_t)scan_row * V);
            for (int j = tid; j < V4; j += T) {
                const float4 t = t4[j]; const int base = j << 2;
                if (t.x > bv) { bv = t.x; bi = base;     }
                if (t.y > bv) { bv = t.y; bi = base + 1; }
                if (t.z > bv) { bv = t.z; bi = base + 2; }
                if (t.w > bv) { bv = t.w; bi = base + 3; }
            }
            for (int j = (V4 << 2) + tid; j < V; j += T) {
                const float tv = tp[(size_t)scan_row * V + j];
                if (tv > bv) { bv = tv; bi = j; }
            }
        } else {
            const float4* t4 = (const float4*)(tp + (size_t)scan_row * V);
            const float4* d4 = (const float4*)(dp + (size_t)scan_row * V);
            const float4* q4 = (const float4*)(q  + (size_t)b * V);
            for (int j = tid; j < V4; j += T) {
                const float4 t = t4[j], d = d4[j], qq = q4[j];
                const int base = j << 2;
                float r;
                r = fmaxf(t.x - d.x, 0.0f) / qq.x; if (r > bv) { bv = r; bi = base;     }
                r = fmaxf(t.y - d.y, 0.0f) / qq.y; if (r > bv) { bv = r; bi = base + 1; }
                r = fmaxf(t.z - d.z, 0.0f) / qq.z; if (r > bv) { bv = r; bi = base + 2; }
                r = fmaxf(t.w - d.w, 0.0f) / qq.w; if (r > bv) { bv = r; bi = base + 3; }
            }
            for (int j = (V4 << 2) + tid; j < V; j += T) {
                const float r = fmaxf(tp[(size_t)scan_row * V + j]
                                      - dp[(size_t)scan_row * V + j], 0.0f)
                                / q[(size_t)b * V + j];
                if (r > bv) { bv = r; bi = j; }
            }
        }
        block_argmax(bv, bi, s_v, s_i);
    }

    // ---- finalize ----
    if (!g) {
        if (tid == 0) {
            for (int p = 0; p < fr; ++p) row[p] = did[start + p];
            if (fr < len) {
                row[fr] = bi;                       // recovered token
                for (int r = fr + 1; r <= S; ++r) row[r] = PLACEHOLDER;
            } else {
                row[len] = bonus[b];                // all accepted -> bonus
                for (int r = len + 1; r <= S; ++r) row[r] = PLACEHOLDER;
            }
        }
        return;
    }

    // greedy: row 0's argmax scanned above
    if (tid == 0) row[0] = bi;
    bool ok = (did[start] == bi);
    int p = 1;
    for (; p < len && ok; ++p) {   // statistically never entered (match prob ~1/V)
        const float4* t4 = (const float4*)(tp + (size_t)(start + p) * V);
        float cv = 0.0f; int ci = 0x7FFFFFFF;
        for (int j = tid; j < V4; j += T) {
            const float4 t = t4[j]; const int base = j << 2;
            if (t.x > cv) { cv = t.x; ci = base;     }
            if (t.y > cv) { cv = t.y; ci = base + 1; }
            if (t.z > cv) { cv = t.z; ci = base + 2; }
            if (t.w > cv) { cv = t.w; ci = base + 3; }
        }
        for (int j = (V4 << 2) + tid; j < V; j += T) {
            const float tv = tp[(size_t)(start + p) * V + j];
            if (tv > cv) { cv = tv; ci = j; }
        }
        block_argmax(cv, ci, s_v, s_i);
        if (tid == 0) row[p] = ci;
        ok = (did[start + p] == ci);
    }
    if (tid == 0) {
        for (int r = p; r <= S; ++r) row[r] = PLACEHOLDER;
        if (ok) row[len] = bonus[b];
    }
}

extern "C" void kernel_launch(void* const* d_in, const int* in_sizes, int n_in,
                              void* d_out, int out_size, void* d_ws, size_t ws_size,
                              hipStream_t stream) {
    const float* dp  = (const float*)d_in[0];   // draft_probs  [N,V]
    const float* tp  = (const float*)d_in[1];   // target_probs [N,V]
    const float* up  = (const float*)d_in[2];   // uniform_probs [N]
    const float* q   = (const float*)d_in[3];   // q [B,V]
    const int*   cu  = (const int*)d_in[4];     // cu_num_draft_tokens [B]
    const int*   did = (const int*)d_in[5];     // draft_token_ids [N]
    const int*   bon = (const int*)d_in[6];     // bonus_token_ids [B]
    const void*  grd = d_in[7];                 // is_greedy [B]

    const int B = in_sizes[4];
    const int N = in_sizes[5];
    const int V = in_sizes[0] / N;
    const int S = out_size / B - 1;

    // single graph node: no workspace, no memset, no atomics, no fences
    fused_one<<<B, T, 0, stream>>>(dp, tp, up, q, cu, did, bon, grd,
                                   (int*)d_out, B, V, S);
}

// Round 8
// 17.535 us; speedup vs baseline: 12.4628x; 1.0021x over previous
//
#include <hip/hip_runtime.h>

#define PLACEHOLDER (-1)
#define T  1024   // threads per block (one block per request)
#define NW (T / 64)

__device__ __forceinline__ void comb(float& v, int& i, float v2, int i2) {
    // argmax combine, numpy tie-break: lower index wins on equal value
    if (v2 > v || (v2 == v && i2 < i)) { v = v2; i = i2; }
}

// block-wide argmax; result broadcast to all threads
__device__ __forceinline__ void block_argmax(float& bv, int& bi, float* s_v, int* s_i) {
    #pragma unroll
    for (int off = 32; off > 0; off >>= 1) {
        float v2 = __shfl_down(bv, off);
        int   i2 = __shfl_down(bi, off);
        comb(bv, bi, v2, i2);
    }
    const int tid = threadIdx.x;
    if ((tid & 63) == 0) { s_v[tid >> 6] = bv; s_i[tid >> 6] = bi; }
    __syncthreads();
    if (tid == 0) {
        for (int w = 1; w < NW; ++w) comb(bv, bi, s_v[w], s_i[w]);
        s_v[0] = bv; s_i[0] = bi;
    }
    __syncthreads();
    bv = s_v[0]; bi = s_i[0];
    __syncthreads();
}

// is_greedy may arrive as 1-byte bools, int32, or float32 — detect from content
__device__ __forceinline__ bool detect_greedy(const void* grd, int b, int B, int* s_flags) {
    const int tid = threadIdx.x;
    if (tid < 2) s_flags[tid] = 0;
    __syncthreads();
    const unsigned char* gb = (const unsigned char*)grd;
    for (int t = tid; t < B; t += T) {
        unsigned char c = gb[t];
        if (c > 1) s_flags[0] = 1;          // bytes beyond {0,1} -> f32 payload
        if ((t & 3) && c) s_flags[1] = 1;   // nonzero off-word byte -> byte bools
    }
    __syncthreads();
    bool g;
    if (s_flags[0])      g = (((const float*)grd)[b] != 0.0f);
    else if (s_flags[1]) g = (gb[b] != 0);
    else                 g = (((const int*)grd)[b] != 0);
    return g;
}

#define PROC_T(t, base)                                   \
    do {                                                  \
        if ((t).x > bv) { bv = (t).x; bi = (base);     }  \
        if ((t).y > bv) { bv = (t).y; bi = (base) + 1; }  \
        if ((t).z > bv) { bv = (t).z; bi = (base) + 2; }  \
        if ((t).w > bv) { bv = (t).w; bi = (base) + 3; }  \
    } while (0)

#define PROC_R(t, d, qq, base)                                                  \
    do {                                                                        \
        float r_;                                                               \
        r_ = fmaxf((t).x - (d).x, 0.0f) / (qq).x; if (r_ > bv) { bv = r_; bi = (base);     } \
        r_ = fmaxf((t).y - (d).y, 0.0f) / (qq).y; if (r_ > bv) { bv = r_; bi = (base) + 1; } \
        r_ = fmaxf((t).z - (d).z, 0.0f) / (qq).z; if (r_ > bv) { bv = r_; bi = (base) + 2; } \
        r_ = fmaxf((t).w - (d).w, 0.0f) / (qq).w; if (r_ > bv) { bv = r_; bi = (base) + 3; } \
    } while (0)

__global__ __launch_bounds__(T) void fused_one(
    const float* __restrict__ dp, const float* __restrict__ tp,
    const float* __restrict__ up, const float* __restrict__ q,
    const int* __restrict__ cu, const int* __restrict__ did,
    const int* __restrict__ bonus, const void* __restrict__ grd,
    int* __restrict__ out, int B, int V, int S)
{
    const int b = blockIdx.x, tid = threadIdx.x;
    __shared__ int   s_flags[2];
    __shared__ float s_v[NW];
    __shared__ int   s_i[NW];
    __shared__ int   sh_fr;

    const bool g    = detect_greedy(grd, b, B, s_flags);
    const int start = b ? cu[b - 1] : 0;
    const int len   = cu[b] - start;
    const int V4    = V >> 2;
    int* row = out + b * (S + 1);

    // ---- prepass: all accept-gathers in parallel (wave 0), ballot -> first reject ----
    int fr = len, scan_row = -1, kind = 0;
    if (g) {
        scan_row = start; kind = 1;       // greedy: row 0 target argmax needed
    } else {
        if (tid < 64) {
            bool acc = true;
            if (tid < len) {
                const int i  = start + tid;
                const int td = did[i];
                const float dat = dp[(size_t)i * V + td];
                const float tat = tp[(size_t)i * V + td];
                acc = (dat > 0.0f && tat >= up[i] * dat);
            }
            const unsigned long long rej =
                (~__ballot(acc)) & ((len >= 64) ? ~0ull : ((1ull << len) - 1ull));
            if (tid == 0) sh_fr = rej ? (__ffsll((long long)rej) - 1) : len;
        }
        __syncthreads();
        fr = sh_fr;
        if (fr < len) scan_row = start + fr;   // first rejected row: recovery scan
    }

    // ---- one heavy scan (if needed), 2-deep software pipeline for MLP ----
    float bv = 0.0f; int bi = 0x7FFFFFFF;   // loses all ties; safe for idle lanes
    if (scan_row >= 0) {
        if (kind) {
            const float4* t4 = (const float4*)(tp + (size_t)scan_row * V);
            int j = tid;
            for (; j + T < V4; j += 2 * T) {
                const float4 ta = t4[j];
                const float4 tb = t4[j + T];
                PROC_T(ta, j << 2);
                PROC_T(tb, (j + T) << 2);
            }
            for (; j < V4; j += T) { const float4 t = t4[j]; PROC_T(t, j << 2); }
            for (int j2 = (V4 << 2) + tid; j2 < V; j2 += T) {
                const float tv = tp[(size_t)scan_row * V + j2];
                if (tv > bv) { bv = tv; bi = j2; }
            }
        } else {
            const float4* t4 = (const float4*)(tp + (size_t)scan_row * V);
            const float4* d4 = (const float4*)(dp + (size_t)scan_row * V);
            const float4* q4 = (const float4*)(q  + (size_t)b * V);
            int j = tid;
            for (; j + T < V4; j += 2 * T) {
                // issue all 6 loads before any compare: 2x in-flight bytes
                const float4 ta = t4[j],     da = d4[j],     qa = q4[j];
                const float4 tb = t4[j + T], db = d4[j + T], qb = q4[j + T];
                PROC_R(ta, da, qa, j << 2);
                PROC_R(tb, db, qb, (j + T) << 2);
            }
            for (; j < V4; j += T) {
                const float4 t = t4[j], d = d4[j], qq = q4[j];
                PROC_R(t, d, qq, j << 2);
            }
            for (int j2 = (V4 << 2) + tid; j2 < V; j2 += T) {
                const float r = fmaxf(tp[(size_t)scan_row * V + j2]
                                      - dp[(size_t)scan_row * V + j2], 0.0f)
                                / q[(size_t)b * V + j2];
                if (r > bv) { bv = r; bi = j2; }
            }
        }
        block_argmax(bv, bi, s_v, s_i);
    }

    // ---- finalize ----
    if (!g) {
        if (tid == 0) {
            for (int p = 0; p < fr; ++p) row[p] = did[start + p];
            if (fr < len) {
                row[fr] = bi;                       // recovered token
                for (int r = fr + 1; r <= S; ++r) row[r] = PLACEHOLDER;
            } else {
                row[len] = bonus[b];                // all accepted -> bonus
                for (int r = len + 1; r <= S; ++r) row[r] = PLACEHOLDER;
            }
        }
        return;
    }

    // greedy: row 0's argmax scanned above
    if (tid == 0) row[0] = bi;
    bool ok = (did[start] == bi);
    int p = 1;
    for (; p < len && ok; ++p) {   // statistically never entered (match prob ~1/V)
        const float4* t4 = (const float4*)(tp + (size_t)(start + p) * V);
        float cv = 0.0f; int ci = 0x7FFFFFFF;
        for (int j = tid; j < V4; j += T) {
            const float4 t = t4[j]; const int base = j << 2;
            if (t.x > cv) { cv = t.x; ci = base;     }
            if (t.y > cv) { cv = t.y; ci = base + 1; }
            if (t.z > cv) { cv = t.z; ci = base + 2; }
            if (t.w > cv) { cv = t.w; ci = base + 3; }
        }
        for (int j = (V4 << 2) + tid; j < V; j += T) {
            const float tv = tp[(size_t)(start + p) * V + j];
            if (tv > cv) { cv = tv; ci = j; }
        }
        block_argmax(cv, ci, s_v, s_i);
        if (tid == 0) row[p] = ci;
        ok = (did[start + p] == ci);
    }
    if (tid == 0) {
        for (int r = p; r <= S; ++r) row[r] = PLACEHOLDER;
        if (ok) row[len] = bonus[b];
    }
}

extern "C" void kernel_launch(void* const* d_in, const int* in_sizes, int n_in,
                              void* d_out, int out_size, void* d_ws, size_t ws_size,
                              hipStream_t stream) {
    const float* dp  = (const float*)d_in[0];   // draft_probs  [N,V]
    const float* tp  = (const float*)d_in[1];   // target_probs [N,V]
    const float* up  = (const float*)d_in[2];   // uniform_probs [N]
    const float* q   = (const float*)d_in[3];   // q [B,V]
    const int*   cu  = (const int*)d_in[4];     // cu_num_draft_tokens [B]
    const int*   did = (const int*)d_in[5];     // draft_token_ids [N]
    const int*   bon = (const int*)d_in[6];     // bonus_token_ids [B]
    const void*  grd = d_in[7];                 // is_greedy [B]

    const int B = in_sizes[4];
    const int N = in_sizes[5];
    const int V = in_sizes[0] / N;
    const int S = out_size / B - 1;

    // single graph node: no workspace, no memset, no atomics, no fences
    fused_one<<<B, T, 0, stream>>>(dp, tp, up, q, cu, did, bon, grd,
                                   (int*)d_out, B, V, S);
}

// Round 9
// 17.505 us; speedup vs baseline: 12.4846x; 1.0017x over previous
//
#include <hip/hip_runtime.h>

#define PLACEHOLDER (-1)
#define T  1024   // threads per block (one block per request)
#define NW (T / 64)

__device__ __forceinline__ void comb(float& v, int& i, float v2, int i2) {
    // argmax combine, numpy tie-break: lower index wins on equal value
    if (v2 > v || (v2 == v && i2 < i)) { v = v2; i = i2; }
}

// block-wide argmax, single barrier: leaders write, everyone combines locally.
// Result broadcast to all threads. Callers must ensure s_v/s_i not in use.
__device__ __forceinline__ void block_argmax(float& bv, int& bi, float* s_v, int* s_i) {
    #pragma unroll
    for (int off = 32; off > 0; off >>= 1) {
        float v2 = __shfl_down(bv, off);
        int   i2 = __shfl_down(bi, off);
        comb(bv, bi, v2, i2);
    }
    const int tid = threadIdx.x;
    if ((tid & 63) == 0) { s_v[tid >> 6] = bv; s_i[tid >> 6] = bi; }
    __syncthreads();
    float rv = s_v[0]; int ri = s_i[0];
    #pragma unroll
    for (int w = 1; w < NW; ++w) comb(rv, ri, s_v[w], s_i[w]);
    bv = rv; bi = ri;
}

#define PROC_T(t, base)                                   \
    do {                                                  \
        if ((t).x > bv) { bv = (t).x; bi = (base);     }  \
        if ((t).y > bv) { bv = (t).y; bi = (base) + 1; }  \
        if ((t).z > bv) { bv = (t).z; bi = (base) + 2; }  \
        if ((t).w > bv) { bv = (t).w; bi = (base) + 3; }  \
    } while (0)

#define PROC_R(t, d, qq, base)                                                  \
    do {                                                                        \
        float r_;                                                               \
        r_ = fmaxf((t).x - (d).x, 0.0f) / (qq).x; if (r_ > bv) { bv = r_; bi = (base);     } \
        r_ = fmaxf((t).y - (d).y, 0.0f) / (qq).y; if (r_ > bv) { bv = r_; bi = (base) + 1; } \
        r_ = fmaxf((t).z - (d).z, 0.0f) / (qq).z; if (r_ > bv) { bv = r_; bi = (base) + 2; } \
        r_ = fmaxf((t).w - (d).w, 0.0f) / (qq).w; if (r_ > bv) { bv = r_; bi = (base) + 3; } \
    } while (0)

__global__ __launch_bounds__(T) void fused_one(
    const float* __restrict__ dp, const float* __restrict__ tp,
    const float* __restrict__ up, const float* __restrict__ q,
    const int* __restrict__ cu, const int* __restrict__ did,
    const int* __restrict__ bonus, const void* __restrict__ grd,
    int* __restrict__ out, int B, int V, int S)
{
    const int b = blockIdx.x, tid = threadIdx.x;
    __shared__ float s_v[NW];
    __shared__ int   s_i[NW];
    __shared__ int   sh_g, sh_fr;

    const int start = b ? cu[b - 1] : 0;
    const int len   = cu[b] - start;
    const int V4    = V >> 2;
    int* row = out + b * (S + 1);

    // ---- wave 0: is_greedy encoding detection + accept prepass, ONE barrier ----
    // is_greedy may arrive as 1-byte bools, int32, or float32.
    if (tid < 64) {
        bool f0 = false, f1 = false;
        for (int t = tid; t * 4 < B; t += 64) {
            const unsigned w = ((const unsigned*)grd)[t];
            if (w & 0xFEFEFEFEu) f0 = true;   // any byte >1 -> f32 payload
            if (w & 0x01010100u) f1 = true;   // nonzero off-word byte -> byte bools
        }
        const bool enc_f32  = (__ballot(f0) != 0ull);
        const bool enc_byte = !enc_f32 && (__ballot(f1) != 0ull);
        const bool g = enc_f32  ? (((const float*)grd)[b] != 0.0f)
                     : enc_byte ? (((const unsigned char*)grd)[b] != 0)
                                : (((const int*)grd)[b] != 0);
        int fr = len;
        if (!g) {
            bool acc = true;
            if (tid < len) {
                const int i  = start + tid;
                const int td = did[i];
                const float dat = dp[(size_t)i * V + td];
                const float tat = tp[(size_t)i * V + td];
                acc = (dat > 0.0f && tat >= up[i] * dat);
            }
            const unsigned long long rej =
                (~__ballot(acc)) & ((len >= 64) ? ~0ull : ((1ull << len) - 1ull));
            fr = rej ? (__ffsll((long long)rej) - 1) : len;
        }
        if (tid == 0) { sh_g = g ? 1 : 0; sh_fr = fr; }
    }
    __syncthreads();
    const bool g  = (sh_g != 0);
    const int  fr = sh_fr;

    int scan_row = -1, kind = 0;
    if (g)            { scan_row = start;      kind = 1; }
    else if (fr < len){ scan_row = start + fr; kind = 0; }

    // ---- one heavy scan (if needed), 2-deep software pipeline ----
    float bv = 0.0f; int bi = 0x7FFFFFFF;   // loses all ties; safe for idle lanes
    if (scan_row >= 0) {
        if (kind) {
            const float4* t4 = (const float4*)(tp + (size_t)scan_row * V);
            int j = tid;
            for (; j + T < V4; j += 2 * T) {
                const float4 ta = t4[j];
                const float4 tb = t4[j + T];
                PROC_T(ta, j << 2);
                PROC_T(tb, (j + T) << 2);
            }
            for (; j < V4; j += T) { const float4 t = t4[j]; PROC_T(t, j << 2); }
            for (int j2 = (V4 << 2) + tid; j2 < V; j2 += T) {
                const float tv = tp[(size_t)scan_row * V + j2];
                if (tv > bv) { bv = tv; bi = j2; }
            }
        } else {
            const float4* t4 = (const float4*)(tp + (size_t)scan_row * V);
            const float4* d4 = (const float4*)(dp + (size_t)scan_row * V);
            const float4* q4 = (const float4*)(q  + (size_t)b * V);
            int j = tid;
            for (; j + T < V4; j += 2 * T) {
                const float4 ta = t4[j],     da = d4[j],     qa = q4[j];
                const float4 tb = t4[j + T], db = d4[j + T], qb = q4[j + T];
                PROC_R(ta, da, qa, j << 2);
                PROC_R(tb, db, qb, (j + T) << 2);
            }
            for (; j < V4; j += T) {
                const float4 t = t4[j], d = d4[j], qq = q4[j];
                PROC_R(t, d, qq, j << 2);
            }
            for (int j2 = (V4 << 2) + tid; j2 < V; j2 += T) {
                const float r = fmaxf(tp[(size_t)scan_row * V + j2]
                                      - dp[(size_t)scan_row * V + j2], 0.0f)
                                / q[(size_t)b * V + j2];
                if (r > bv) { bv = r; bi = j2; }
            }
        }
        block_argmax(bv, bi, s_v, s_i);   // one barrier; bi broadcast to all
    }

    // ---- finalize: one thread per output slot ----
    if (!g) {
        if (tid <= S) {
            int val;
            if (tid < fr)       val = did[start + tid];
            else if (fr < len)  val = (tid == fr)  ? bi       : PLACEHOLDER;
            else                val = (tid == len) ? bonus[b] : PLACEHOLDER;
            row[tid] = val;
        }
        return;
    }

    // greedy: row 0's argmax in bi
    const int tok0 = bi;
    const bool ok0 = (did[start] == tok0);
    if (!ok0 || len == 1) {
        if (tid <= S) {
            int val = PLACEHOLDER;
            if (tid == 0) val = tok0;
            else if (ok0 && tid == len) val = bonus[b];   // len==1 all-accepted
            row[tid] = val;
        }
        return;
    }
    // statistically-never continuation (draft matched argmax, len>1)
    if (tid == 0) row[0] = tok0;
    bool ok = true;
    int p = 1;
    for (; p < len && ok; ++p) {
        __syncthreads();   // protect s_v/s_i reuse
        const float4* t4 = (const float4*)(tp + (size_t)(start + p) * V);
        float cv = 0.0f; int ci = 0x7FFFFFFF;
        for (int j = tid; j < V4; j += T) {
            const float4 t = t4[j]; const int base = j << 2;
            if (t.x > cv) { cv = t.x; ci = base;     }
            if (t.y > cv) { cv = t.y; ci = base + 1; }
            if (t.z > cv) { cv = t.z; ci = base + 2; }
            if (t.w > cv) { cv = t.w; ci = base + 3; }
        }
        for (int j = (V4 << 2) + tid; j < V; j += T) {
            const float tv = tp[(size_t)(start + p) * V + j];
            if (tv > cv) { cv = tv; ci = j; }
        }
        block_argmax(cv, ci, s_v, s_i);
        if (tid == 0) row[p] = ci;
        ok = (did[start + p] == ci);
    }
    if (tid == 0) {
        for (int r = p; r <= S; ++r) row[r] = PLACEHOLDER;
        if (ok) row[len] = bonus[b];
    }
}

extern "C" void kernel_launch(void* const* d_in, const int* in_sizes, int n_in,
                              void* d_out, int out_size, void* d_ws, size_t ws_size,
                              hipStream_t stream) {
    const float* dp  = (const float*)d_in[0];   // draft_probs  [N,V]
    const float* tp  = (const float*)d_in[1];   // target_probs [N,V]
    const float* up  = (const float*)d_in[2];   // uniform_probs [N]
    const float* q   = (const float*)d_in[3];   // q [B,V]
    const int*   cu  = (const int*)d_in[4];     // cu_num_draft_tokens [B]
    const int*   did = (const int*)d_in[5];     // draft_token_ids [N]
    const int*   bon = (const int*)d_in[6];     // bonus_token_ids [B]
    const void*  grd = d_in[7];                 // is_greedy [B]

    const int B = in_sizes[4];
    const int N = in_sizes[5];
    const int V = in_sizes[0] / N;
    const int S = out_size / B - 1;

    // single graph node: no workspace, no memset, no atomics, no fences
    fused_one<<<B, T, 0, stream>>>(dp, tp, up, q, cu, did, bon, grd,
                                   (int*)d_out, B, V, S);
}